// Round 2
// baseline (518.193 us; speedup 1.0000x reference)
//
#include <hip/hip_runtime.h>
#include <math.h>

#define BATCH 8
#define LSEQ  1024
#define NH    8
#define EDIM  64
#define LF    513      // LSEQ/2 + 1
#define NBH   64       // BATCH * NH
#define XT    8        // x rows per attention block

// ---------------- 1024-point Stockham radix-2 FFT (512 threads) ----------------
// b0 holds input; result lands back in b0 in natural order. tw[j] = (cos, sin)(2*pi*j/1024).
// sign = -1 forward, +1 inverse (no 1/N scaling applied here).
__device__ __forceinline__ void fft_stages(float2* src, float2* dst,
                                           const float2* __restrict__ tw,
                                           int t, float sign) {
  int s = 1, ls = 0, n = 1024;
  #pragma unroll
  for (int st = 0; st < 10; st++) {
    int m = n >> 1;
    int p = t >> ls;
    int q = t & (s - 1);
    float2 a = src[q + s * p];
    float2 b = src[q + s * p + s * m];
    float2 w = tw[p * s];
    float wr = w.x, wi = sign * w.y;
    float2 r0 = make_float2(a.x + b.x, a.y + b.y);
    float2 d  = make_float2(a.x - b.x, a.y - b.y);
    float2 r1 = make_float2(d.x * wr - d.y * wi, d.x * wi + d.y * wr);
    dst[q + s * 2 * p]     = r0;
    dst[q + s * 2 * p + s] = r1;
    __syncthreads();
    float2* tmp = src; src = dst; dst = tmp;
    n >>= 1; s <<= 1; ls++;
  }
}

// ---------------- K1: rfft of q,k,v (two real rows packed per complex FFT) ------
// out layout: dst[bh][x][e*2 + {re,im}]  (128 floats per frequency row)
__global__ __launch_bounds__(512) void rfft_pack_kernel(
    const float* __restrict__ q, const float* __restrict__ k, const float* __restrict__ v,
    float* __restrict__ qf, float* __restrict__ kf, float* __restrict__ vf) {
  __shared__ float2 b0[1024];
  __shared__ float2 b1[1024];
  __shared__ float2 tw[512];
  const int t = threadIdx.x;
  const int epair = blockIdx.x;   // 0..31
  const int bh = blockIdx.y;      // 0..63
  const int tensor = blockIdx.z;  // 0..2
  const int b = bh >> 3, h = bh & 7;
  const int e = epair * 2;
  const float* src = (tensor == 0) ? q : ((tensor == 1) ? k : v);
  float* dst = (tensor == 0) ? qf : ((tensor == 1) ? kf : vf);

  if (t < 512) {
    float sv, cv;
    sincosf(6.2831853071795864769f * (float)t * (1.0f / 1024.0f), &sv, &cv);
    tw[t] = make_float2(cv, sv);
  }
  #pragma unroll
  for (int i = 0; i < 2; i++) {
    int l = t + i * 512;
    const float* p = src + (((size_t)b * LSEQ + l) * NH + h) * EDIM + e;
    b0[l] = make_float2(p[0], p[1]);
  }
  __syncthreads();
  fft_stages(b0, b1, tw, t, -1.0f);
  // unpack: A = (Z[k]+conj(Z[N-k]))/2, B = (Z[k]-conj(Z[N-k]))/(2i); scale 1/sqrt(1024)
  #pragma unroll
  for (int i = 0; i < 2; i++) {
    int kk = t + i * 512;
    if (kk <= 512) {
      float2 z  = b0[kk];
      float2 zn = b0[(1024 - kk) & 1023];
      const float sc = 0.03125f * 0.5f;
      float ar = sc * (z.x + zn.x);
      float ai = sc * (z.y - zn.y);
      float br = sc * (z.y + zn.y);
      float bi = sc * (zn.x - z.x);
      float* o = dst + ((size_t)bh * LF + kk) * (EDIM * 2) + e * 2;
      o[0] = ar; o[1] = ai; o[2] = br; o[3] = bi;
    }
  }
}

// ---------------- K2: fused scores + softmax + PV ------------------------------
__global__ __launch_bounds__(256) void attn_kernel(
    const float* __restrict__ qf, const float* __restrict__ kf,
    const float* __restrict__ vf, float* __restrict__ of) {
  const int bh  = blockIdx.y;
  const int x0  = blockIdx.x * XT;
  const int tid = threadIdx.x;

  __shared__ float qe[32][XT][4];    // [e4][xi][{re0,im0,re1,im1}]
  __shared__ float mag[XT][LF];      // phase A out; reused as reduction scratch
  __shared__ float attn2[LF][XT];    // unnormalized exp weights, transposed
  __shared__ float winv[XT];

  // load q columns (zero-pad x tail)
  for (int i = tid; i < XT * 128; i += 256) {
    int xi = i >> 7, c = i & 127;
    int e = c >> 1, comp = c & 1;
    int x = x0 + xi;
    float val = 0.0f;
    if (x < LF) val = qf[((size_t)bh * LF + x) * 128 + c];
    qe[e >> 1][xi][(e & 1) * 2 + comp] = val;
  }
  __syncthreads();

  // ---- Phase A: |scores| / sqrt(E) ----
  for (int y = tid; y < LF; y += 256) {
    const float4* kr = (const float4*)(kf + ((size_t)bh * LF + y) * 128);
    float accr[XT], acci[XT];
    #pragma unroll
    for (int xi = 0; xi < XT; xi++) { accr[xi] = 0.f; acci[xi] = 0.f; }
    #pragma unroll 4
    for (int e4 = 0; e4 < 32; e4++) {
      float4 kv = kr[e4];
      #pragma unroll
      for (int xi = 0; xi < XT; xi++) {
        float4 qv = *(const float4*)qe[e4][xi];
        accr[xi] += qv.x * kv.x + qv.y * kv.y + qv.z * kv.z + qv.w * kv.w;
        acci[xi] += qv.y * kv.x - qv.x * kv.y + qv.w * kv.z - qv.z * kv.w;
      }
    }
    #pragma unroll
    for (int xi = 0; xi < XT; xi++)
      mag[xi][y] = 0.125f * sqrtf(accr[xi] * accr[xi] + acci[xi] * acci[xi]);
  }
  __syncthreads();

  // ---- Phase B: softmax over y (normalization deferred via winv) ----
  {
    int wave = tid >> 6, lane = tid & 63;
    #pragma unroll
    for (int r = 0; r < 2; r++) {
      int row = wave * 2 + r;
      float mx = -1e30f;
      for (int y = lane; y < LF; y += 64) mx = fmaxf(mx, mag[row][y]);
      #pragma unroll
      for (int o = 32; o > 0; o >>= 1) mx = fmaxf(mx, __shfl_xor(mx, o));
      float s = 0.f;
      for (int y = lane; y < LF; y += 64) {
        float ev = __expf(mag[row][y] - mx);
        s += ev;
        attn2[y][row] = ev;
      }
      #pragma unroll
      for (int o = 32; o > 0; o >>= 1) s += __shfl_xor(s, o);
      if (lane == 0) winv[row] = 1.0f / s;
    }
  }
  __syncthreads();

  // ---- Phase C: outf[x][c] = sum_y attn[x][y] * vf[y][c] ----
  const int g = tid >> 5;     // 0..7, y-phase
  const int l32 = tid & 31;   // float4 column
  float acc[XT][4];
  #pragma unroll
  for (int xi = 0; xi < XT; xi++)
    #pragma unroll
    for (int j = 0; j < 4; j++) acc[xi][j] = 0.f;

  for (int y = g; y < LF; y += 8) {
    float4 vv = *(const float4*)(vf + ((size_t)bh * LF + y) * 128 + l32 * 4);
    float4 a0 = *(const float4*)&attn2[y][0];
    float4 a1 = *(const float4*)&attn2[y][4];
    #pragma unroll
    for (int j = 0; j < 4; j++) {
      float vj = (j == 0) ? vv.x : (j == 1) ? vv.y : (j == 2) ? vv.z : vv.w;
      acc[0][j] += a0.x * vj; acc[1][j] += a0.y * vj;
      acc[2][j] += a0.z * vj; acc[3][j] += a0.w * vj;
      acc[4][j] += a1.x * vj; acc[5][j] += a1.y * vj;
      acc[6][j] += a1.z * vj; acc[7][j] += a1.w * vj;
    }
  }

  // tree-reduce the 8 y-phases through LDS (mag is dead; reuse as scratch)
  float* red = &mag[0][0];   // 4104 floats >= 4096 needed
  __syncthreads();
  if (g >= 4) {
    #pragma unroll
    for (int xi = 0; xi < XT; xi++)
      #pragma unroll
      for (int j = 0; j < 4; j++)
        red[(g - 4) * 1024 + (xi * 32 + l32) * 4 + j] = acc[xi][j];
  }
  __syncthreads();
  if (g < 4) {
    #pragma unroll
    for (int xi = 0; xi < XT; xi++)
      #pragma unroll
      for (int j = 0; j < 4; j++)
        acc[xi][j] += red[g * 1024 + (xi * 32 + l32) * 4 + j];
  }
  __syncthreads();
  if (g >= 2 && g < 4) {
    #pragma unroll
    for (int xi = 0; xi < XT; xi++)
      #pragma unroll
      for (int j = 0; j < 4; j++)
        red[(g - 2) * 1024 + (xi * 32 + l32) * 4 + j] = acc[xi][j];
  }
  __syncthreads();
  if (g < 2) {
    #pragma unroll
    for (int xi = 0; xi < XT; xi++)
      #pragma unroll
      for (int j = 0; j < 4; j++)
        acc[xi][j] += red[g * 1024 + (xi * 32 + l32) * 4 + j];
  }
  __syncthreads();
  if (g == 1) {
    #pragma unroll
    for (int xi = 0; xi < XT; xi++)
      #pragma unroll
      for (int j = 0; j < 4; j++)
        red[(xi * 32 + l32) * 4 + j] = acc[xi][j];
  }
  __syncthreads();
  if (g == 0) {
    #pragma unroll
    for (int xi = 0; xi < XT; xi++) {
      int x = x0 + xi;
      if (x < LF) {
        float wv = winv[xi];
        float4 o;
        o.x = (acc[xi][0] + red[(xi * 32 + l32) * 4 + 0]) * wv;
        o.y = (acc[xi][1] + red[(xi * 32 + l32) * 4 + 1]) * wv;
        o.z = (acc[xi][2] + red[(xi * 32 + l32) * 4 + 2]) * wv;
        o.w = (acc[xi][3] + red[(xi * 32 + l32) * 4 + 3]) * wv;
        *(float4*)(of + ((size_t)bh * LF + x) * 128 + l32 * 4) = o;
      }
    }
  }
}

// ---------------- K3: irfft via conjugate-symmetric packing --------------------
__global__ __launch_bounds__(512) void irfft_kernel(
    const float* __restrict__ of, float* __restrict__ out) {
  __shared__ float2 b0[1024];
  __shared__ float2 b1[1024];
  __shared__ float2 tw[512];
  const int t = threadIdx.x;
  const int epair = blockIdx.x;   // 0..31
  const int bh = blockIdx.y;      // 0..63
  const int b = bh >> 3, h = bh & 7;
  const int e = epair * 2;

  if (t < 512) {
    float sv, cv;
    sincosf(6.2831853071795864769f * (float)t * (1.0f / 1024.0f), &sv, &cv);
    tw[t] = make_float2(cv, sv);
  }
  // build G[k] = F_a[k] + i F_b[k], mirror with conjugates for k > 512
  #pragma unroll
  for (int i = 0; i < 2; i++) {
    int kk = t + i * 512;
    if (kk <= 512) {
      const float* p = of + ((size_t)bh * LF + kk) * 128 + e * 2;
      float far = p[0], fai = p[1], fbr = p[2], fbi = p[3];
      b0[kk] = make_float2(far - fbi, fai + fbr);
      if (kk >= 1 && kk <= 511) {
        b0[1024 - kk] = make_float2(far + fbi, fbr - fai);
      }
    }
  }
  __syncthreads();
  fft_stages(b0, b1, tw, t, +1.0f);
  // x_a = Re(z)/sqrt(N), x_b = Im(z)/sqrt(N); write [b][l][h][e]
  #pragma unroll
  for (int i = 0; i < 2; i++) {
    int l = t + i * 512;
    float2 z = b0[l];
    float* o = out + (((size_t)b * LSEQ + l) * NH + h) * EDIM + e;
    o[0] = 0.03125f * z.x;
    o[1] = 0.03125f * z.y;
  }
}

extern "C" void kernel_launch(void* const* d_in, const int* in_sizes, int n_in,
                              void* d_out, int out_size, void* d_ws, size_t ws_size,
                              hipStream_t stream) {
  const float* q = (const float*)d_in[0];
  const float* k = (const float*)d_in[1];
  const float* v = (const float*)d_in[2];
  float* out = (float*)d_out;
  float* ws = (float*)d_ws;

  const size_t per = (size_t)NBH * LF * (EDIM * 2);  // 4,202,496 floats
  float* qf = ws;
  float* kf = qf + per;
  float* vf = kf + per;
  float* of = vf + per;
  // total workspace: 4 * per * 4 bytes = 67,239,936 B

  rfft_pack_kernel<<<dim3(32, NBH, 3), 512, 0, stream>>>(q, k, v, qf, kf, vf);
  attn_kernel<<<dim3((LF + XT - 1) / XT, NBH), 256, 0, stream>>>(qf, kf, vf, of);
  irfft_kernel<<<dim3(32, NBH), 512, 0, stream>>>(of, out);
}

// Round 3
// 352.615 us; speedup vs baseline: 1.4696x; 1.4696x over previous
//
#include <hip/hip_runtime.h>
#include <hip/hip_fp16.h>
#include <math.h>

#define BATCH 8
#define LSEQ  1024
#define NH    8
#define EDIM  64
#define LF    513      // LSEQ/2 + 1
#define NBH   64       // BATCH * NH
#define YP    576      // LF padded to multiple of 64

typedef _Float16 f16;
typedef _Float16 f16x8 __attribute__((ext_vector_type(8)));
typedef float    f32x4 __attribute__((ext_vector_type(4)));
typedef unsigned int u32x4 __attribute__((ext_vector_type(4)));

// ---------------- 1024-point Stockham radix-2 FFT (512 threads) ----------------
__device__ __forceinline__ void fft_stages(float2* src, float2* dst,
                                           const float2* __restrict__ tw,
                                           int t, float sign) {
  int s = 1, ls = 0, n = 1024;
  #pragma unroll
  for (int st = 0; st < 10; st++) {
    int m = n >> 1;
    int p = t >> ls;
    int q = t & (s - 1);
    float2 a = src[q + s * p];
    float2 b = src[q + s * p + s * m];
    float2 w = tw[p * s];
    float wr = w.x, wi = sign * w.y;
    float2 r0 = make_float2(a.x + b.x, a.y + b.y);
    float2 d  = make_float2(a.x - b.x, a.y - b.y);
    float2 r1 = make_float2(d.x * wr - d.y * wi, d.x * wi + d.y * wr);
    dst[q + s * 2 * p]     = r0;
    dst[q + s * 2 * p + s] = r1;
    __syncthreads();
    float2* tmp = src; src = dst; dst = tmp;
    n >>= 1; s <<= 1; ls++;
  }
}

// ---------------- K1: rfft of q,k,v -> fp16 workspace --------------------------
// qf/kf: [bh][YP][128] fp16 (re/im interleaved along c); rows >= 513 left as-is.
// vfT  : [bh][128][YP] fp16 transposed; y in [513,576) zero-filled.
__global__ __launch_bounds__(512) void rfft_pack_kernel(
    const float* __restrict__ q, const float* __restrict__ k, const float* __restrict__ v,
    f16* __restrict__ qf, f16* __restrict__ kf, f16* __restrict__ vfT) {
  __shared__ float2 b0[1024];
  __shared__ float2 b1[1024];
  __shared__ float2 tw[512];
  const int t = threadIdx.x;
  const int epair = blockIdx.x;   // 0..31
  const int bh = blockIdx.y;      // 0..63
  const int tensor = blockIdx.z;  // 0..2
  const int b = bh >> 3, h = bh & 7;
  const int e = epair * 2;
  const float* src = (tensor == 0) ? q : ((tensor == 1) ? k : v);

  float sv, cv;
  __sincosf(6.2831853071795864769f * (float)t * (1.0f / 1024.0f), &sv, &cv);
  tw[t] = make_float2(cv, sv);
  #pragma unroll
  for (int i = 0; i < 2; i++) {
    int l = t + i * 512;
    const float* p = src + (((size_t)b * LSEQ + l) * NH + h) * EDIM + e;
    b0[l] = make_float2(p[0], p[1]);
  }
  __syncthreads();
  fft_stages(b0, b1, tw, t, -1.0f);
  #pragma unroll
  for (int i = 0; i < 2; i++) {
    int kk = t + i * 512;
    if (kk <= 512) {
      float2 z  = b0[kk];
      float2 zn = b0[(1024 - kk) & 1023];
      const float sc = 0.03125f * 0.5f;
      float ar = sc * (z.x + zn.x);
      float ai = sc * (z.y - zn.y);
      float br = sc * (z.y + zn.y);
      float bi = sc * (zn.x - z.x);
      if (tensor < 2) {
        f16* dst = (tensor == 0) ? qf : kf;
        union { f16 h[4]; uint2 u; } pk;
        pk.h[0] = (f16)ar; pk.h[1] = (f16)ai; pk.h[2] = (f16)br; pk.h[3] = (f16)bi;
        *(uint2*)(dst + ((size_t)bh * YP + kk) * 128 + e * 2) = pk.u;
      } else {
        size_t base = (size_t)bh * 128 + e * 2;
        vfT[(base + 0) * YP + kk] = (f16)ar;
        vfT[(base + 1) * YP + kk] = (f16)ai;
        vfT[(base + 2) * YP + kk] = (f16)br;
        vfT[(base + 3) * YP + kk] = (f16)bi;
      }
    }
  }
  if (tensor == 2 && t < 63) {
    int kk = 513 + t;
    size_t base = (size_t)bh * 128 + e * 2;
    #pragma unroll
    for (int j = 0; j < 4; j++) vfT[(base + j) * YP + kk] = (f16)0.0f;
  }
}

// ---------------- K2a: scores (complex MFMA) + magnitude softmax ----------------
// block = (xtile of 64 rows, bh); 4 waves, wave w owns rows w*16..w*16+15.
__global__ __launch_bounds__(256) void scores_softmax_kernel(
    const f16* __restrict__ qf, const f16* __restrict__ kf,
    f16* __restrict__ p, float* __restrict__ winv) {
  __shared__ f16 mag[64][588];   // stride 588: lane-groups hit disjoint bank octets
  const int tid = threadIdx.x;
  const int w = tid >> 6, l = tid & 63, lr = l & 15, lg = l >> 4;
  const int bh = blockIdx.y, x0 = blockIdx.x * 64;

  // A-fragments of q (and the conj-swizzled variant for the imaginary part)
  const f16* qb = qf + ((size_t)bh * YP + x0 + w * 16 + lr) * 128 + lg * 8;
  f16x8 aq[4], aqs[4];
  #pragma unroll
  for (int c4 = 0; c4 < 4; c4++) {
    aq[c4] = *(const f16x8*)(qb + c4 * 32);
    u32x4 tt = *(const u32x4*)&aq[c4];
    u32x4 ss;
    #pragma unroll
    for (int d = 0; d < 4; d++)
      ss[d] = ((tt[d] >> 16) | (tt[d] << 16)) ^ 0x80000000u;  // (re,im)->(im,-re)
    aqs[c4] = *(const f16x8*)&ss;
  }

  const f16* kb = kf + ((size_t)bh * YP + lr) * 128 + lg * 8;
  for (int yt2 = 0; yt2 < 18; yt2++) {
    const int y0 = yt2 * 32;
    f16x8 bA[4], bB[4];
    #pragma unroll
    for (int c4 = 0; c4 < 4; c4++) {
      bA[c4] = *(const f16x8*)(kb + (size_t)(y0)      * 128 + c4 * 32);
      bB[c4] = *(const f16x8*)(kb + (size_t)(y0 + 16) * 128 + c4 * 32);
    }
    f32x4 rA = {0.f,0.f,0.f,0.f}, iA = {0.f,0.f,0.f,0.f};
    f32x4 rB = {0.f,0.f,0.f,0.f}, iB = {0.f,0.f,0.f,0.f};
    #pragma unroll
    for (int c4 = 0; c4 < 4; c4++) {
      rA = __builtin_amdgcn_mfma_f32_16x16x32_f16(aq[c4],  bA[c4], rA, 0, 0, 0);
      iA = __builtin_amdgcn_mfma_f32_16x16x32_f16(aqs[c4], bA[c4], iA, 0, 0, 0);
      rB = __builtin_amdgcn_mfma_f32_16x16x32_f16(aq[c4],  bB[c4], rB, 0, 0, 0);
      iB = __builtin_amdgcn_mfma_f32_16x16x32_f16(aqs[c4], bB[c4], iB, 0, 0, 0);
    }
    const int row = w * 16 + lg * 4;
    #pragma unroll
    for (int i = 0; i < 4; i++) {
      mag[row + i][y0 + lr]      = (f16)(0.125f * sqrtf(rA[i]*rA[i] + iA[i]*iA[i]));
      mag[row + i][y0 + 16 + lr] = (f16)(0.125f * sqrtf(rB[i]*rB[i] + iB[i]*iB[i]));
    }
  }

  // Phase 2: per-row softmax (wave reads only its own rows -> no block barrier)
  for (int r = 0; r < 16; r++) {
    const int row = w * 16 + r;
    float mx = 0.0f;   // mags >= 0
    #pragma unroll
    for (int t4 = 0; t4 < 4; t4++) {
      __half2 hv = *(const __half2*)&mag[row][2 * l + 128 * t4];
      float2 f = __half22float2(hv);
      mx = fmaxf(mx, fmaxf(f.x, f.y));
    }
    if (l < 32) {
      __half2 hv = *(const __half2*)&mag[row][2 * l + 512];
      float2 f = __half22float2(hv);
      mx = fmaxf(mx, fmaxf(f.x, f.y));
    }
    #pragma unroll
    for (int o = 32; o > 0; o >>= 1) mx = fmaxf(mx, __shfl_xor(mx, o));

    float s = 0.0f;
    f16* prow = p + ((size_t)bh * YP + x0 + row) * YP;
    #pragma unroll
    for (int t4 = 0; t4 < 4; t4++) {
      __half2 hv = *(const __half2*)&mag[row][2 * l + 128 * t4];
      float2 f = __half22float2(hv);
      float p0 = __expf(f.x - mx), p1 = __expf(f.y - mx);
      s += p0 + p1;
      *(__half2*)(prow + 2 * l + 128 * t4) = __floats2half2_rn(p0, p1);
    }
    if (l < 32) {
      int y = 2 * l + 512;
      __half2 hv = *(const __half2*)&mag[row][y];
      float2 f = __half22float2(hv);
      float p0 = (y < LF) ? __expf(f.x - mx) : 0.0f;   // mask padded y
      s += p0;
      *(__half2*)(prow + y) = __floats2half2_rn(p0, 0.0f);
    }
    #pragma unroll
    for (int o = 32; o > 0; o >>= 1) s += __shfl_xor(s, o);
    if (l == 0) winv[bh * YP + x0 + row] = 1.0f / s;
  }
}

// ---------------- K2b: PV GEMM (p[fp16] x vfT[fp16] -> of[fp32]) ----------------
__global__ __launch_bounds__(256) void pv_kernel(
    const f16* __restrict__ p, const f16* __restrict__ vfT,
    const float* __restrict__ winv, float* __restrict__ of) {
  const int tid = threadIdx.x;
  const int w = tid >> 6, l = tid & 63, lr = l & 15, lg = l >> 4;
  const int bh = blockIdx.y, x0 = blockIdx.x * 64;

  const f16* pb = p   + ((size_t)bh * YP + x0 + w * 16 + lr) * YP + lg * 8;
  const f16* vb = vfT + ((size_t)bh * 128 + lr) * YP + lg * 8;
  f32x4 acc[8];
  #pragma unroll
  for (int nt = 0; nt < 8; nt++) acc[nt] = (f32x4){0.f, 0.f, 0.f, 0.f};

  for (int kc = 0; kc < 18; kc++) {
    f16x8 a = *(const f16x8*)(pb + kc * 32);
    #pragma unroll
    for (int nt = 0; nt < 8; nt++) {
      f16x8 b = *(const f16x8*)(vb + (size_t)nt * 16 * YP + kc * 32);
      acc[nt] = __builtin_amdgcn_mfma_f32_16x16x32_f16(a, b, acc[nt], 0, 0, 0);
    }
  }
  const int xr = x0 + w * 16 + lg * 4;
  #pragma unroll
  for (int i = 0; i < 4; i++) {
    if (xr + i < LF) {
      float wv = winv[bh * YP + xr + i];
      #pragma unroll
      for (int nt = 0; nt < 8; nt++)
        of[((size_t)bh * LF + xr + i) * 128 + nt * 16 + lr] = acc[nt][i] * wv;
    }
  }
}

// ---------------- K3: irfft via conjugate-symmetric packing --------------------
__global__ __launch_bounds__(512) void irfft_kernel(
    const float* __restrict__ of, float* __restrict__ out) {
  __shared__ float2 b0[1024];
  __shared__ float2 b1[1024];
  __shared__ float2 tw[512];
  const int t = threadIdx.x;
  const int epair = blockIdx.x;   // 0..31
  const int bh = blockIdx.y;      // 0..63
  const int b = bh >> 3, h = bh & 7;
  const int e = epair * 2;

  float sv, cv;
  __sincosf(6.2831853071795864769f * (float)t * (1.0f / 1024.0f), &sv, &cv);
  tw[t] = make_float2(cv, sv);
  #pragma unroll
  for (int i = 0; i < 2; i++) {
    int kk = t + i * 512;
    if (kk <= 512) {
      const float* p = of + ((size_t)bh * LF + kk) * 128 + e * 2;
      float far = p[0], fai = p[1], fbr = p[2], fbi = p[3];
      b0[kk] = make_float2(far - fbi, fai + fbr);
      if (kk >= 1 && kk <= 511) {
        b0[1024 - kk] = make_float2(far + fbi, fbr - fai);
      }
    }
  }
  __syncthreads();
  fft_stages(b0, b1, tw, t, +1.0f);
  #pragma unroll
  for (int i = 0; i < 2; i++) {
    int l = t + i * 512;
    float2 z = b0[l];
    float* o = out + (((size_t)b * LSEQ + l) * NH + h) * EDIM + e;
    o[0] = 0.03125f * z.x;
    o[1] = 0.03125f * z.y;
  }
}

extern "C" void kernel_launch(void* const* d_in, const int* in_sizes, int n_in,
                              void* d_out, int out_size, void* d_ws, size_t ws_size,
                              hipStream_t stream) {
  const float* q = (const float*)d_in[0];
  const float* k = (const float*)d_in[1];
  const float* v = (const float*)d_in[2];
  float* out = (float*)d_out;
  char* ws = (char*)d_ws;

  // Workspace layout (bytes):
  //   qf16 : [0,          9437184)   64*576*128 fp16
  //   kf16 : [9437184,   18874368)
  //   vfT  : [18874368,  28311552)   64*128*576 fp16 (transposed, y-padded)
  //   p    : [28311552,  70778880)   64*576*576 fp16
  //   winv : [70778880,  70926336)   64*576 fp32
  //   of   : aliases [0, 16809984)   (qf/kf dead when pv_kernel writes it)
  // total required: 70,926,336 B
  f16*   qf   = (f16*)(ws);
  f16*   kf   = (f16*)(ws + 9437184);
  f16*   vfT  = (f16*)(ws + 18874368);
  f16*   p    = (f16*)(ws + 28311552);
  float* winv = (float*)(ws + 70778880);
  float* of   = (float*)(ws);

  rfft_pack_kernel<<<dim3(32, NBH, 3), 512, 0, stream>>>(q, k, v, qf, kf, vfT);
  scores_softmax_kernel<<<dim3(9, NBH), 256, 0, stream>>>(qf, kf, p, winv);
  pv_kernel<<<dim3(9, NBH), 256, 0, stream>>>(p, vfT, winv, of);
  irfft_kernel<<<dim3(32, NBH), 512, 0, stream>>>(of, out);
}

// Round 5
// 309.040 us; speedup vs baseline: 1.6768x; 1.1410x over previous
//
#include <hip/hip_runtime.h>
#include <hip/hip_fp16.h>
#include <math.h>

#define BATCH 8
#define LSEQ  1024
#define NH    8
#define EDIM  64
#define LF    513      // LSEQ/2 + 1
#define NBH   64       // BATCH * NH
#define YP    576      // LF padded to multiple of 64

typedef _Float16 f16;
typedef _Float16 f16x8 __attribute__((ext_vector_type(8)));
typedef float    f32x4 __attribute__((ext_vector_type(4)));
typedef unsigned int u32x4 __attribute__((ext_vector_type(4)));

// ---------------- 1024-point Stockham radix-2 FFT (512 threads) ----------------
__device__ __forceinline__ void fft_stages(float2* src, float2* dst,
                                           const float2* __restrict__ tw,
                                           int t, float sign) {
  int s = 1, ls = 0, n = 1024;
  #pragma unroll
  for (int st = 0; st < 10; st++) {
    int m = n >> 1;
    int p = t >> ls;
    int q = t & (s - 1);
    float2 a = src[q + s * p];
    float2 b = src[q + s * p + s * m];
    float2 w = tw[p * s];
    float wr = w.x, wi = sign * w.y;
    float2 r0 = make_float2(a.x + b.x, a.y + b.y);
    float2 d  = make_float2(a.x - b.x, a.y - b.y);
    float2 r1 = make_float2(d.x * wr - d.y * wi, d.x * wi + d.y * wr);
    dst[q + s * 2 * p]     = r0;
    dst[q + s * 2 * p + s] = r1;
    __syncthreads();
    float2* tmp = src; src = dst; dst = tmp;
    n >>= 1; s <<= 1; ls++;
  }
}

// ---------------- K1: rfft of q,k,v -> fp16 workspace --------------------------
// qf/kf: [bh][YP][128] fp16 (re/im interleaved along c); rows >= 513 left as-is.
// vfT  : [bh][128][YP] fp16 transposed; y in [513,576) zero-filled.
__global__ __launch_bounds__(512) void rfft_pack_kernel(
    const float* __restrict__ q, const float* __restrict__ k, const float* __restrict__ v,
    f16* __restrict__ qf, f16* __restrict__ kf, f16* __restrict__ vfT) {
  __shared__ float2 b0[1024];
  __shared__ float2 b1[1024];
  __shared__ float2 tw[512];
  const int t = threadIdx.x;
  const int epair = blockIdx.x;   // 0..31
  const int bh = blockIdx.y;      // 0..63
  const int tensor = blockIdx.z;  // 0..2
  const int b = bh >> 3, h = bh & 7;
  const int e = epair * 2;
  const float* src = (tensor == 0) ? q : ((tensor == 1) ? k : v);

  float sv, cv;
  __sincosf(6.2831853071795864769f * (float)t * (1.0f / 1024.0f), &sv, &cv);
  tw[t] = make_float2(cv, sv);
  #pragma unroll
  for (int i = 0; i < 2; i++) {
    int l = t + i * 512;
    const float* p = src + (((size_t)b * LSEQ + l) * NH + h) * EDIM + e;
    b0[l] = make_float2(p[0], p[1]);
  }
  __syncthreads();
  fft_stages(b0, b1, tw, t, -1.0f);
  #pragma unroll
  for (int i = 0; i < 2; i++) {
    int kk = t + i * 512;
    if (kk <= 512) {
      float2 z  = b0[kk];
      float2 zn = b0[(1024 - kk) & 1023];
      const float sc = 0.03125f * 0.5f;
      float ar = sc * (z.x + zn.x);
      float ai = sc * (z.y - zn.y);
      float br = sc * (z.y + zn.y);
      float bi = sc * (zn.x - z.x);
      if (tensor < 2) {
        f16* dst = (tensor == 0) ? qf : kf;
        union { f16 h[4]; uint2 u; } pk;
        pk.h[0] = (f16)ar; pk.h[1] = (f16)ai; pk.h[2] = (f16)br; pk.h[3] = (f16)bi;
        *(uint2*)(dst + ((size_t)bh * YP + kk) * 128 + e * 2) = pk.u;
      } else {
        size_t base = (size_t)bh * 128 + e * 2;
        vfT[(base + 0) * YP + kk] = (f16)ar;
        vfT[(base + 1) * YP + kk] = (f16)ai;
        vfT[(base + 2) * YP + kk] = (f16)br;
        vfT[(base + 3) * YP + kk] = (f16)bi;
      }
    }
  }
  if (tensor == 2 && t < 63) {
    int kk = 513 + t;
    size_t base = (size_t)bh * 128 + e * 2;
    #pragma unroll
    for (int j = 0; j < 4; j++) vfT[(base + j) * YP + kk] = (f16)0.0f;
  }
}

// ---------------- K2: fused scores + softmax + PV ------------------------------
// block: 32 x-rows, full y. 4 waves: phase A wave = (x-sub, y-half);
// p kept in swizzled LDS; phase C wave = (x-sub, c-half).
__device__ __forceinline__ int pmidx(int row, int y) {
  return row * YP + (y ^ ((row & 7) << 3));   // 16B-granule XOR swizzle
}

__global__ __launch_bounds__(256, 4) void fused_attn_kernel(
    const f16* __restrict__ qf, const f16* __restrict__ kf,
    const f16* __restrict__ vfT, float* __restrict__ of) {
  __shared__ f16 pm[32 * YP];      // 36,864 B: mag, then p (in place)
  __shared__ float winv_s[32];
  const int tid = threadIdx.x;
  const int w = tid >> 6, l = tid & 63, lr = l & 15, lg = l >> 4;
  const int bh = blockIdx.y, x0 = blockIdx.x * 32;
  const int xsub = w & 1, yhalf = w >> 1;

  // Pre-zero the padded tail. Under the swizzle this writes, per row,
  // slots 512+({0..63} \ {(row&7)<<3}); phase A's y=512 write lands exactly
  // on 512+((row&7)<<3) -> complete coverage, no overlap, no barrier needed.
  for (int i = tid; i < 2048; i += 256) {
    int row = i >> 6, yo = i & 63;
    if (yo) pm[pmidx(row, 512 + yo)] = (f16)0.0f;
  }

  // ---- Phase A: |scores|/sqrt(E) for rows xsub*16.., y-half ----
  const f16* qb = qf + ((size_t)bh * YP + x0 + xsub * 16 + lr) * 128 + lg * 8;
  f16x8 aq[4], aqs[4];
  #pragma unroll
  for (int c4 = 0; c4 < 4; c4++) {
    aq[c4] = *(const f16x8*)(qb + c4 * 32);
    u32x4 tt = *(const u32x4*)&aq[c4];
    u32x4 ss;
    #pragma unroll
    for (int d = 0; d < 4; d++)
      ss[d] = ((tt[d] >> 16) | (tt[d] << 16)) ^ 0x80000000u;  // (re,im)->(im,-re)
    aqs[c4] = *(const f16x8*)&ss;
  }

  const int ntile = yhalf ? 15 : 18;   // y-half 1 stops after y=527 tile
  const f16* kb = kf + ((size_t)bh * YP + yhalf * 288 + lr) * 128 + lg * 8;
  for (int t = 0; t < ntile; t++) {
    f16x8 bk[4];
    #pragma unroll
    for (int c4 = 0; c4 < 4; c4++)
      bk[c4] = *(const f16x8*)(kb + (size_t)(t * 16) * 128 + c4 * 32);
    f32x4 rr = {0.f,0.f,0.f,0.f}, ri = {0.f,0.f,0.f,0.f};
    #pragma unroll
    for (int c4 = 0; c4 < 4; c4++) {
      rr = __builtin_amdgcn_mfma_f32_16x16x32_f16(aq[c4],  bk[c4], rr, 0, 0, 0);
      ri = __builtin_amdgcn_mfma_f32_16x16x32_f16(aqs[c4], bk[c4], ri, 0, 0, 0);
    }
    int y = yhalf * 288 + t * 16 + lr;
    if (y <= 512) {
      int rowb = xsub * 16 + lg * 4;
      #pragma unroll
      for (int i = 0; i < 4; i++)
        pm[pmidx(rowb + i, y)] = (f16)(0.125f * sqrtf(rr[i]*rr[i] + ri[i]*ri[i]));
    }
  }
  __syncthreads();

  // ---- Phase B: per-row softmax (wave w owns rows w*8..w*8+7) ----
  #pragma unroll 1
  for (int r = 0; r < 8; r++) {
    const int row = w * 8 + r;
    float mx = 0.0f;   // mags >= 0
    #pragma unroll
    for (int ps = 0; ps < 4; ps++) {
      __half2 hv = *(const __half2*)&pm[pmidx(row, 2 * (l + 64 * ps))];
      float2 f = __half22float2(hv);
      mx = fmaxf(mx, fmaxf(f.x, f.y));
    }
    if (l < 32) {   // tail: include y=512 in the max (513.. are pre-zeroed)
      __half2 hv = *(const __half2*)&pm[pmidx(row, 512 + 2 * l)];
      float2 f = __half22float2(hv);
      mx = fmaxf(mx, fmaxf(f.x, f.y));
    }
    #pragma unroll
    for (int o = 32; o > 0; o >>= 1) mx = fmaxf(mx, __shfl_xor(mx, o));

    float s = 0.0f;
    #pragma unroll
    for (int ps = 0; ps < 4; ps++) {
      int y = 2 * (l + 64 * ps);
      __half2 hv = *(const __half2*)&pm[pmidx(row, y)];
      float2 f = __half22float2(hv);
      float p0 = __expf(f.x - mx), p1 = __expf(f.y - mx);
      s += p0 + p1;
      *(__half2*)&pm[pmidx(row, y)] = __floats2half2_rn(p0, p1);
    }
    if (l < 32) {
      int y = 512 + 2 * l;
      __half2 hv = *(const __half2*)&pm[pmidx(row, y)];
      float2 f = __half22float2(hv);
      float p0 = (y <= 512) ? __expf(f.x - mx) : 0.0f;
      s += p0;
      *(__half2*)&pm[pmidx(row, y)] = __floats2half2_rn(p0, 0.0f);
    }
    #pragma unroll
    for (int o = 32; o > 0; o >>= 1) s += __shfl_xor(s, o);
    if (l == 0) winv_s[row] = 1.0f / s;
  }
  __syncthreads();

  // ---- Phase C: PV. wave = (xsub, c-half); A-frags from swizzled LDS ----
  const int ch = (w >> 1) * 64;
  f32x4 acc[4];
  #pragma unroll
  for (int nt = 0; nt < 4; nt++) acc[nt] = (f32x4){0.f,0.f,0.f,0.f};
  const f16* vb = vfT + ((size_t)bh * 128 + ch + lr) * YP + lg * 8;
  for (int kc = 0; kc < 18; kc++) {
    f16x8 a = *(const f16x8*)&pm[pmidx(xsub * 16 + lr, kc * 32 + lg * 8)];
    #pragma unroll
    for (int nt = 0; nt < 4; nt++) {
      f16x8 b = *(const f16x8*)(vb + (size_t)(nt * 16) * YP + kc * 32);
      acc[nt] = __builtin_amdgcn_mfma_f32_16x16x32_f16(a, b, acc[nt], 0, 0, 0);
    }
  }
  #pragma unroll
  for (int i = 0; i < 4; i++) {
    int xl = xsub * 16 + lg * 4 + i;
    int x = x0 + xl;
    if (x < LF) {
      float wv = winv_s[xl];
      #pragma unroll
      for (int nt = 0; nt < 4; nt++)
        of[((size_t)bh * LF + x) * 128 + ch + nt * 16 + lr] = acc[nt][i] * wv;
    }
  }
}

// ---------------- K3: irfft via conjugate-symmetric packing --------------------
__global__ __launch_bounds__(512) void irfft_kernel(
    const float* __restrict__ of, float* __restrict__ out) {
  __shared__ float2 b0[1024];
  __shared__ float2 b1[1024];
  __shared__ float2 tw[512];
  const int t = threadIdx.x;
  const int epair = blockIdx.x;   // 0..31
  const int bh = blockIdx.y;      // 0..63
  const int b = bh >> 3, h = bh & 7;
  const int e = epair * 2;

  float sv, cv;
  __sincosf(6.2831853071795864769f * (float)t * (1.0f / 1024.0f), &sv, &cv);
  tw[t] = make_float2(cv, sv);
  #pragma unroll
  for (int i = 0; i < 2; i++) {
    int kk = t + i * 512;
    if (kk <= 512) {
      const float* p = of + ((size_t)bh * LF + kk) * 128 + e * 2;
      float far = p[0], fai = p[1], fbr = p[2], fbi = p[3];
      b0[kk] = make_float2(far - fbi, fai + fbr);
      if (kk >= 1 && kk <= 511) {
        b0[1024 - kk] = make_float2(far + fbi, fbr - fai);
      }
    }
  }
  __syncthreads();
  fft_stages(b0, b1, tw, t, +1.0f);
  #pragma unroll
  for (int i = 0; i < 2; i++) {
    int l = t + i * 512;
    float2 z = b0[l];
    float* o = out + (((size_t)b * LSEQ + l) * NH + h) * EDIM + e;
    o[0] = 0.03125f * z.x;
    o[1] = 0.03125f * z.y;
  }
}

extern "C" void kernel_launch(void* const* d_in, const int* in_sizes, int n_in,
                              void* d_out, int out_size, void* d_ws, size_t ws_size,
                              hipStream_t stream) {
  const float* q = (const float*)d_in[0];
  const float* k = (const float*)d_in[1];
  const float* v = (const float*)d_in[2];
  float* out = (float*)d_out;
  char* ws = (char*)d_ws;

  // Workspace layout (bytes):
  //   qf16 : [0,          9437184)   64*576*128 fp16
  //   kf16 : [9437184,   18874368)
  //   vfT  : [18874368,  28311552)   64*128*576 fp16 (transposed, y-padded)
  //   of   : [28311552,  45121536)   64*513*128 fp32
  f16*   qf  = (f16*)(ws);
  f16*   kf  = (f16*)(ws + 9437184);
  f16*   vfT = (f16*)(ws + 18874368);
  float* of  = (float*)(ws + 28311552);

  rfft_pack_kernel<<<dim3(32, NBH, 3), 512, 0, stream>>>(q, k, v, qf, kf, vfT);
  fused_attn_kernel<<<dim3(17, NBH), 256, 0, stream>>>(qf, kf, vfT, of);
  irfft_kernel<<<dim3(32, NBH), 512, 0, stream>>>(of, out);
}

// Round 6
// 262.519 us; speedup vs baseline: 1.9739x; 1.1772x over previous
//
#include <hip/hip_runtime.h>
#include <hip/hip_fp16.h>
#include <math.h>

#define BATCH 8
#define LSEQ  1024
#define NH    8
#define EDIM  64
#define LF    513      // LSEQ/2 + 1
#define NBH   64       // BATCH * NH
#define YP    576      // LF padded to multiple of 64

typedef _Float16 f16;
typedef _Float16 f16x8 __attribute__((ext_vector_type(8)));
typedef float    f32x4 __attribute__((ext_vector_type(4)));
typedef unsigned int u32x4 __attribute__((ext_vector_type(4)));

__device__ __forceinline__ float2 cadd(float2 a, float2 b){return make_float2(a.x+b.x, a.y+b.y);}
__device__ __forceinline__ float2 csub(float2 a, float2 b){return make_float2(a.x-b.x, a.y-b.y);}
__device__ __forceinline__ float2 cmuls(float2 w, float2 y, float sign){
  float wr = w.x, wi = sign * w.y;
  return make_float2(y.x*wr - y.y*wi, y.x*wi + y.y*wr);
}

// ---------------- radix-4 Stockham, N=1024 = 4^5 -------------------------------
// Read base = bt; write base = 4*bt - 3*q. tw[j] = (cos,sin)(2*pi*j/1024), j<768.
template<int ST>
__device__ __forceinline__ void r4stage(const float2* S, float2* D,
                                        const float2* __restrict__ tw,
                                        int bt, float sign) {
  const int s = 1 << (2*ST);
  const int q = bt & (s - 1);
  const int j1 = bt - q;                 // = p*s
  float2 a0 = S[bt], a1 = S[bt+256], a2 = S[bt+512], a3 = S[bt+768];
  float2 b0 = cadd(a0,a2), b1 = csub(a0,a2);
  float2 b2 = cadd(a1,a3), b3 = csub(a1,a3);
  float2 y0 = cadd(b0,b2), y2 = csub(b0,b2);
  float2 ib3 = make_float2(-sign*b3.y, sign*b3.x);   // sign*i*b3
  float2 y1 = cadd(b1, ib3), y3 = csub(b1, ib3);
  const int wb = 4*bt - 3*q;
  D[wb]       = y0;
  D[wb +   s] = cmuls(tw[j1],   y1, sign);
  D[wb + 2*s] = cmuls(tw[2*j1], y2, sign);
  D[wb + 3*s] = cmuls(tw[3*j1], y3, sign);
}

// two interleaved 1024-pt FFTs; 512 threads; result lands in fb1.
__device__ __forceinline__ void fft1024x2_r4(float2* fb0, float2* fb1,
                                             const float2* __restrict__ tw,
                                             int t, float sign) {
  const int off = (t >> 8) << 10;   // which FFT
  const int bt  = t & 255;
  r4stage<0>(fb0+off, fb1+off, tw, bt, sign); __syncthreads();
  r4stage<1>(fb1+off, fb0+off, tw, bt, sign); __syncthreads();
  r4stage<2>(fb0+off, fb1+off, tw, bt, sign); __syncthreads();
  r4stage<3>(fb1+off, fb0+off, tw, bt, sign); __syncthreads();
  r4stage<4>(fb0+off, fb1+off, tw, bt, sign); __syncthreads();
}

// ---------------- K1: rfft of q,k,v -> fp16 workspace --------------------------
// Block = (equad: 4 e-values = 2 packed real-pair FFTs, bh, tensor).
// qf/kf: [bh][YP][128] fp16; vfT: [bh][128][YP] fp16 transposed, y-tail zeroed.
__global__ __launch_bounds__(512) void rfft_pack_kernel(
    const float* __restrict__ q, const float* __restrict__ k, const float* __restrict__ v,
    f16* __restrict__ qf, f16* __restrict__ kf, f16* __restrict__ vfT) {
  __shared__ float2 fb0[2048];
  __shared__ float2 fb1[2048];
  __shared__ float2 tw[768];
  const int t = threadIdx.x;
  const int equad = blockIdx.x;   // 0..15
  const int bh = blockIdx.y;      // 0..63
  const int tensor = blockIdx.z;  // 0..2
  const int b = bh >> 3, h = bh & 7;
  const int e0 = equad * 4;
  const float* src = (tensor == 0) ? q : ((tensor == 1) ? k : v);

  for (int i = t; i < 768; i += 512) {
    float sv, cv;
    __sincosf(6.2831853071795864769f * (float)i * (1.0f / 1024.0f), &sv, &cv);
    tw[i] = make_float2(cv, sv);
  }
  #pragma unroll
  for (int i = 0; i < 2; i++) {
    int l = t + i * 512;
    float4 vv = *(const float4*)(src + (((size_t)b * LSEQ + l) * NH + h) * EDIM + e0);
    fb0[l]        = make_float2(vv.x, vv.y);
    fb0[1024 + l] = make_float2(vv.z, vv.w);
  }
  __syncthreads();
  fft1024x2_r4(fb0, fb1, tw, t, -1.0f);

  #pragma unroll
  for (int i = 0; i < 2; i++) {
    int kk = t + i * 512;
    if (kk <= 512) {
      const float sc = 0.015625f;   // 1/sqrt(1024) * 1/2
      if (tensor < 2) {
        union { f16 hh[8]; u32x4 u; } pk;
        #pragma unroll
        for (int f = 0; f < 2; f++) {
          float2 z  = fb1[(f << 10) + kk];
          float2 zn = fb1[(f << 10) + ((1024 - kk) & 1023)];
          pk.hh[f*4+0] = (f16)(sc * (z.x + zn.x));
          pk.hh[f*4+1] = (f16)(sc * (z.y - zn.y));
          pk.hh[f*4+2] = (f16)(sc * (z.y + zn.y));
          pk.hh[f*4+3] = (f16)(sc * (zn.x - z.x));
        }
        f16* dst = (tensor == 0) ? qf : kf;
        *(u32x4*)(dst + ((size_t)bh * YP + kk) * 128 + e0 * 2) = pk.u;
      } else {
        #pragma unroll
        for (int f = 0; f < 2; f++) {
          float2 z  = fb1[(f << 10) + kk];
          float2 zn = fb1[(f << 10) + ((1024 - kk) & 1023)];
          size_t base = (size_t)bh * 128 + e0 * 2 + f * 4;
          vfT[(base + 0) * YP + kk] = (f16)(sc * (z.x + zn.x));
          vfT[(base + 1) * YP + kk] = (f16)(sc * (z.y - zn.y));
          vfT[(base + 2) * YP + kk] = (f16)(sc * (z.y + zn.y));
          vfT[(base + 3) * YP + kk] = (f16)(sc * (zn.x - z.x));
        }
      }
    }
  }
  if (tensor == 2 && t < 63) {
    int kk = 513 + t;
    #pragma unroll
    for (int j = 0; j < 8; j++)
      vfT[((size_t)bh * 128 + e0 * 2 + j) * YP + kk] = (f16)0.0f;
  }
}

// ---------------- K2: fused scores + softmax + PV ------------------------------
__device__ __forceinline__ int pmidx(int row, int y) {
  return row * YP + (y ^ ((row & 7) << 3));   // 16B-granule XOR swizzle
}

__global__ __launch_bounds__(256, 4) void fused_attn_kernel(
    const f16* __restrict__ qf, const f16* __restrict__ kf,
    const f16* __restrict__ vfT, float* __restrict__ of) {
  __shared__ f16 pm[32 * YP];      // 36,864 B
  __shared__ float winv_s[32];
  const int tid = threadIdx.x;
  const int w = tid >> 6, l = tid & 63, lr = l & 15, lg = l >> 4;
  const int bh = blockIdx.y, x0 = blockIdx.x * 32;
  const int xsub = w & 1, yhalf = w >> 1;

  // Pre-zero padded tail (complete coverage with phase A's y=512 write; no race).
  for (int i = tid; i < 2048; i += 256) {
    int row = i >> 6, yo = i & 63;
    if (yo) pm[pmidx(row, 512 + yo)] = (f16)0.0f;
  }

  // ---- Phase A: |scores|/sqrt(E), depth-1 K prefetch ----
  const f16* qb = qf + ((size_t)bh * YP + x0 + xsub * 16 + lr) * 128 + lg * 8;
  f16x8 aq[4], aqs[4];
  #pragma unroll
  for (int c4 = 0; c4 < 4; c4++) {
    aq[c4] = *(const f16x8*)(qb + c4 * 32);
    u32x4 tt = *(const u32x4*)&aq[c4];
    u32x4 ss;
    #pragma unroll
    for (int d = 0; d < 4; d++)
      ss[d] = ((tt[d] >> 16) | (tt[d] << 16)) ^ 0x80000000u;  // (re,im)->(im,-re)
    aqs[c4] = *(const f16x8*)&ss;
  }

  const int ntile = yhalf ? 15 : 18;
  const f16* kb = kf + ((size_t)bh * YP + yhalf * 288 + lr) * 128 + lg * 8;

  f16x8 kA[4], kB[4];
  #pragma unroll
  for (int c4 = 0; c4 < 4; c4++) kA[c4] = *(const f16x8*)(kb + c4 * 32);

#define PROCA(KR, TT) {                                                        \
    f32x4 rr = {0.f,0.f,0.f,0.f}, ri = {0.f,0.f,0.f,0.f};                      \
    _Pragma("unroll")                                                          \
    for (int c4 = 0; c4 < 4; c4++) {                                           \
      rr = __builtin_amdgcn_mfma_f32_16x16x32_f16(aq[c4],  KR[c4], rr, 0,0,0); \
      ri = __builtin_amdgcn_mfma_f32_16x16x32_f16(aqs[c4], KR[c4], ri, 0,0,0); \
    }                                                                          \
    int y = yhalf * 288 + (TT) * 16 + lr;                                      \
    if (y <= 512) {                                                            \
      int rowb = xsub * 16 + lg * 4;                                           \
      _Pragma("unroll")                                                        \
      for (int i = 0; i < 4; i++)                                              \
        pm[pmidx(rowb + i, y)] = (f16)(0.125f * sqrtf(rr[i]*rr[i] + ri[i]*ri[i])); \
    }                                                                          \
  }

  for (int t = 0; t < ntile; t += 2) {
    if (t + 1 < ntile) {
      const f16* kp = kb + (size_t)(t + 1) * 2048;
      #pragma unroll
      for (int c4 = 0; c4 < 4; c4++) kB[c4] = *(const f16x8*)(kp + c4 * 32);
    }
    PROCA(kA, t)
    if (t + 1 < ntile) {
      if (t + 2 < ntile) {
        const f16* kp = kb + (size_t)(t + 2) * 2048;
        #pragma unroll
        for (int c4 = 0; c4 < 4; c4++) kA[c4] = *(const f16x8*)(kp + c4 * 32);
      }
      PROCA(kB, t + 1)
    }
  }
#undef PROCA
  __syncthreads();

  // ---- Phase B: per-row softmax (wave w owns rows w*8..w*8+7) ----
  #pragma unroll 1
  for (int r = 0; r < 8; r++) {
    const int row = w * 8 + r;
    float mx = 0.0f;
    #pragma unroll
    for (int ps = 0; ps < 4; ps++) {
      __half2 hv = *(const __half2*)&pm[pmidx(row, 2 * (l + 64 * ps))];
      float2 f = __half22float2(hv);
      mx = fmaxf(mx, fmaxf(f.x, f.y));
    }
    if (l < 32) {
      __half2 hv = *(const __half2*)&pm[pmidx(row, 512 + 2 * l)];
      float2 f = __half22float2(hv);
      mx = fmaxf(mx, fmaxf(f.x, f.y));
    }
    #pragma unroll
    for (int o = 32; o > 0; o >>= 1) mx = fmaxf(mx, __shfl_xor(mx, o));

    float s = 0.0f;
    #pragma unroll
    for (int ps = 0; ps < 4; ps++) {
      int y = 2 * (l + 64 * ps);
      __half2 hv = *(const __half2*)&pm[pmidx(row, y)];
      float2 f = __half22float2(hv);
      float p0 = __expf(f.x - mx), p1 = __expf(f.y - mx);
      s += p0 + p1;
      *(__half2*)&pm[pmidx(row, y)] = __floats2half2_rn(p0, p1);
    }
    if (l < 32) {
      int y = 512 + 2 * l;
      __half2 hv = *(const __half2*)&pm[pmidx(row, y)];
      float2 f = __half22float2(hv);
      float p0 = (y <= 512) ? __expf(f.x - mx) : 0.0f;
      s += p0;
      *(__half2*)&pm[pmidx(row, y)] = __floats2half2_rn(p0, 0.0f);
    }
    #pragma unroll
    for (int o = 32; o > 0; o >>= 1) s += __shfl_xor(s, o);
    if (l == 0) winv_s[row] = 1.0f / s;
  }
  __syncthreads();

  // ---- Phase C: PV with depth-1 V prefetch ----
  const int ch = (w >> 1) * 64;
  f32x4 acc[4];
  #pragma unroll
  for (int nt = 0; nt < 4; nt++) acc[nt] = (f32x4){0.f,0.f,0.f,0.f};
  const f16* vb = vfT + ((size_t)bh * 128 + ch + lr) * YP + lg * 8;

  f16x8 vA[4], vB[4];
  #pragma unroll
  for (int nt = 0; nt < 4; nt++) vA[nt] = *(const f16x8*)(vb + (size_t)(nt * 16) * YP);

  for (int kc = 0; kc < 18; kc += 2) {
    #pragma unroll
    for (int nt = 0; nt < 4; nt++)
      vB[nt] = *(const f16x8*)(vb + (size_t)(nt * 16) * YP + (kc + 1) * 32);
    {
      f16x8 a = *(const f16x8*)&pm[pmidx(xsub * 16 + lr, kc * 32 + lg * 8)];
      #pragma unroll
      for (int nt = 0; nt < 4; nt++)
        acc[nt] = __builtin_amdgcn_mfma_f32_16x16x32_f16(a, vA[nt], acc[nt], 0, 0, 0);
    }
    if (kc + 2 < 18) {
      #pragma unroll
      for (int nt = 0; nt < 4; nt++)
        vA[nt] = *(const f16x8*)(vb + (size_t)(nt * 16) * YP + (kc + 2) * 32);
    }
    {
      f16x8 a = *(const f16x8*)&pm[pmidx(xsub * 16 + lr, (kc + 1) * 32 + lg * 8)];
      #pragma unroll
      for (int nt = 0; nt < 4; nt++)
        acc[nt] = __builtin_amdgcn_mfma_f32_16x16x32_f16(a, vB[nt], acc[nt], 0, 0, 0);
    }
  }
  #pragma unroll
  for (int i = 0; i < 4; i++) {
    int xl = xsub * 16 + lg * 4 + i;
    int x = x0 + xl;
    if (x < LF) {
      float wv = winv_s[xl];
      #pragma unroll
      for (int nt = 0; nt < 4; nt++)
        of[((size_t)bh * LF + x) * 128 + ch + nt * 16 + lr] = acc[nt][i] * wv;
    }
  }
}

// ---------------- K3: irfft via conjugate-symmetric packing --------------------
// Block = (equad: 4 e-values = 2 packed inverse FFTs, bh).
__global__ __launch_bounds__(512) void irfft_kernel(
    const float* __restrict__ of, float* __restrict__ out) {
  __shared__ float2 fb0[2048];
  __shared__ float2 fb1[2048];
  __shared__ float2 tw[768];
  const int t = threadIdx.x;
  const int equad = blockIdx.x;   // 0..15
  const int bh = blockIdx.y;      // 0..63
  const int b = bh >> 3, h = bh & 7;
  const int e0 = equad * 4;

  for (int i = t; i < 768; i += 512) {
    float sv, cv;
    __sincosf(6.2831853071795864769f * (float)i * (1.0f / 1024.0f), &sv, &cv);
    tw[i] = make_float2(cv, sv);
  }
  #pragma unroll
  for (int i = 0; i < 2; i++) {
    int kk = t + i * 512;
    if (kk <= 512) {
      const float* pr = of + ((size_t)bh * LF + kk) * 128 + e0 * 2;
      float4 r0 = *(const float4*)pr;
      float4 r1 = *(const float4*)(pr + 4);
      fb0[kk]        = make_float2(r0.x - r0.w, r0.y + r0.z);
      fb0[1024 + kk] = make_float2(r1.x - r1.w, r1.y + r1.z);
      if (kk >= 1 && kk <= 511) {
        fb0[1024 - kk]        = make_float2(r0.x + r0.w, r0.z - r0.y);
        fb0[1024 + 1024 - kk] = make_float2(r1.x + r1.w, r1.z - r1.y);
      }
    }
  }
  __syncthreads();
  fft1024x2_r4(fb0, fb1, tw, t, +1.0f);
  #pragma unroll
  for (int i = 0; i < 2; i++) {
    int l = t + i * 512;
    float2 z0 = fb1[l], z1 = fb1[1024 + l];
    float4 o = make_float4(0.03125f * z0.x, 0.03125f * z0.y,
                           0.03125f * z1.x, 0.03125f * z1.y);
    *(float4*)(out + (((size_t)b * LSEQ + l) * NH + h) * EDIM + e0) = o;
  }
}

extern "C" void kernel_launch(void* const* d_in, const int* in_sizes, int n_in,
                              void* d_out, int out_size, void* d_ws, size_t ws_size,
                              hipStream_t stream) {
  const float* q = (const float*)d_in[0];
  const float* k = (const float*)d_in[1];
  const float* v = (const float*)d_in[2];
  float* out = (float*)d_out;
  char* ws = (char*)d_ws;

  // Workspace layout (bytes):
  //   qf16 : [0,          9437184)   64*576*128 fp16
  //   kf16 : [9437184,   18874368)
  //   vfT  : [18874368,  28311552)   64*128*576 fp16 (transposed, y-padded)
  //   of   : [28311552,  45121536)   64*513*128 fp32
  f16*   qf  = (f16*)(ws);
  f16*   kf  = (f16*)(ws + 9437184);
  f16*   vfT = (f16*)(ws + 18874368);
  float* of  = (float*)(ws + 28311552);

  rfft_pack_kernel<<<dim3(16, NBH, 3), 512, 0, stream>>>(q, k, v, qf, kf, vfT);
  fused_attn_kernel<<<dim3(17, NBH), 256, 0, stream>>>(qf, kf, vfT, of);
  irfft_kernel<<<dim3(16, NBH), 512, 0, stream>>>(of, out);
}

// Round 9
// 250.184 us; speedup vs baseline: 2.0712x; 1.0493x over previous
//
#include <hip/hip_runtime.h>
#include <hip/hip_fp16.h>
#include <math.h>

#define BATCH 8
#define LSEQ  1024
#define NH    8
#define EDIM  64
#define LF    513      // LSEQ/2 + 1
#define NBH   64       // BATCH * NH
#define YP    576      // LF padded to multiple of 64

typedef _Float16 f16;
typedef _Float16 f16x8 __attribute__((ext_vector_type(8)));
typedef float    f32x4 __attribute__((ext_vector_type(4)));
typedef unsigned int u32x4 __attribute__((ext_vector_type(4)));

__device__ __forceinline__ float2 cadd(float2 a, float2 b){return make_float2(a.x+b.x, a.y+b.y);}
__device__ __forceinline__ float2 csub(float2 a, float2 b){return make_float2(a.x-b.x, a.y-b.y);}
__device__ __forceinline__ float2 cmuls(float2 w, float2 y, float sign){
  float wr = w.x, wi = sign * w.y;
  return make_float2(y.x*wr - y.y*wi, y.x*wi + y.y*wr);
}
// LDS anti-conflict swizzle: bijective on [0,1024); turns the 16-way
// stage-0/1 Stockham write conflicts into 4-way (see m136 scaling).
__device__ __forceinline__ int SW(int i){ return i ^ ((i >> 4) & 15); }

// ---------------- radix-4 Stockham, N=1024 = 4^5 -------------------------------
template<int ST>
__device__ __forceinline__ void r4stage(const float2* S, float2* D,
                                        const float2* __restrict__ tw,
                                        int bt, float sign) {
  const int s = 1 << (2*ST);
  const int q = bt & (s - 1);
  const int j1 = bt - q;                 // = p*s
  float2 a0 = S[SW(bt)], a1 = S[SW(bt+256)], a2 = S[SW(bt+512)], a3 = S[SW(bt+768)];
  float2 b0 = cadd(a0,a2), b1 = csub(a0,a2);
  float2 b2 = cadd(a1,a3), b3 = csub(a1,a3);
  float2 y0 = cadd(b0,b2), y2 = csub(b0,b2);
  float2 ib3 = make_float2(-sign*b3.y, sign*b3.x);   // sign*i*b3
  float2 y1 = cadd(b1, ib3), y3 = csub(b1, ib3);
  const int wb = 4*bt - 3*q;
  D[SW(wb)]       = y0;
  D[SW(wb +   s)] = cmuls(tw[j1],   y1, sign);
  D[SW(wb + 2*s)] = cmuls(tw[2*j1], y2, sign);
  D[SW(wb + 3*s)] = cmuls(tw[3*j1], y3, sign);
}

// two interleaved 1024-pt FFTs; 512 threads; result lands in fb1 (swizzled).
__device__ __forceinline__ void fft1024x2_r4(float2* fb0, float2* fb1,
                                             const float2* __restrict__ tw,
                                             int t, float sign) {
  const int off = (t >> 8) << 10;   // which FFT
  const int bt  = t & 255;
  r4stage<0>(fb0+off, fb1+off, tw, bt, sign); __syncthreads();
  r4stage<1>(fb1+off, fb0+off, tw, bt, sign); __syncthreads();
  r4stage<2>(fb0+off, fb1+off, tw, bt, sign); __syncthreads();
  r4stage<3>(fb1+off, fb0+off, tw, bt, sign); __syncthreads();
  r4stage<4>(fb0+off, fb1+off, tw, bt, sign); __syncthreads();
}

// ---------------- K1: rfft of q,k,v -> fp16 workspace --------------------------
// Block = (equad: 4 e-values = 2 packed real-pair FFTs, bh, tensor).
// qf/kf: [bh][YP][128] fp16; vfT: [bh][128][YP] fp16 transposed, y-tail zeroed.
__global__ __launch_bounds__(512) void rfft_pack_kernel(
    const float* __restrict__ q, const float* __restrict__ k, const float* __restrict__ v,
    f16* __restrict__ qf, f16* __restrict__ kf, f16* __restrict__ vfT) {
  __shared__ float2 fb0[2048];
  __shared__ float2 fb1[2048];
  __shared__ float2 tw[768];
  const int t = threadIdx.x;
  const int equad = blockIdx.x;   // 0..15
  const int bh = blockIdx.y;      // 0..63
  const int tensor = blockIdx.z;  // 0..2
  const int b = bh >> 3, h = bh & 7;
  const int e0 = equad * 4;
  const float* src = (tensor == 0) ? q : ((tensor == 1) ? k : v);

  for (int i = t; i < 768; i += 512) {
    float sv, cv;
    __sincosf(6.2831853071795864769f * (float)i * (1.0f / 1024.0f), &sv, &cv);
    tw[i] = make_float2(cv, sv);
  }
  #pragma unroll
  for (int i = 0; i < 2; i++) {
    int l = t + i * 512;
    float4 vv = *(const float4*)(src + (((size_t)b * LSEQ + l) * NH + h) * EDIM + e0);
    fb0[SW(l)]        = make_float2(vv.x, vv.y);
    fb0[1024 + SW(l)] = make_float2(vv.z, vv.w);
  }
  __syncthreads();
  fft1024x2_r4(fb0, fb1, tw, t, -1.0f);

  #pragma unroll
  for (int i = 0; i < 2; i++) {
    int kk = t + i * 512;
    if (kk <= 512) {
      const int kn = (1024 - kk) & 1023;
      const float sc = 0.015625f;   // 1/sqrt(1024) * 1/2
      if (tensor < 2) {
        union { f16 hh[8]; u32x4 u; } pk;
        #pragma unroll
        for (int f = 0; f < 2; f++) {
          float2 z  = fb1[(f << 10) + SW(kk)];
          float2 zn = fb1[(f << 10) + SW(kn)];
          pk.hh[f*4+0] = (f16)(sc * (z.x + zn.x));
          pk.hh[f*4+1] = (f16)(sc * (z.y - zn.y));
          pk.hh[f*4+2] = (f16)(sc * (z.y + zn.y));
          pk.hh[f*4+3] = (f16)(sc * (zn.x - z.x));
        }
        f16* dst = (tensor == 0) ? qf : kf;
        *(u32x4*)(dst + ((size_t)bh * YP + kk) * 128 + e0 * 2) = pk.u;
      } else {
        #pragma unroll
        for (int f = 0; f < 2; f++) {
          float2 z  = fb1[(f << 10) + SW(kk)];
          float2 zn = fb1[(f << 10) + SW(kn)];
          size_t base = (size_t)bh * 128 + e0 * 2 + f * 4;
          vfT[(base + 0) * YP + kk] = (f16)(sc * (z.x + zn.x));
          vfT[(base + 1) * YP + kk] = (f16)(sc * (z.y - zn.y));
          vfT[(base + 2) * YP + kk] = (f16)(sc * (z.y + zn.y));
          vfT[(base + 3) * YP + kk] = (f16)(sc * (zn.x - z.x));
        }
      }
    }
  }
  if (tensor == 2 && t < 63) {
    int kk = 513 + t;
    #pragma unroll
    for (int j = 0; j < 8; j++)
      vfT[((size_t)bh * 128 + e0 * 2 + j) * YP + kk] = (f16)0.0f;
  }
}

// ---------------- K2: fused scores + softmax + PV ------------------------------
// block: 16 x-rows, full y, 6 blocks/CU. Phase A: wave = y-quarter;
// phase B: wave owns 4 rows; phase C: wave = 32-col slice.
__device__ __forceinline__ int pmidx(int row, int y) {
  return row * YP + (y ^ ((row & 7) << 3));   // 16B-granule XOR swizzle
}

__global__ __launch_bounds__(256, 6) void fused_attn_kernel(
    const f16* __restrict__ qf, const f16* __restrict__ kf,
    const f16* __restrict__ vfT, float* __restrict__ of) {
  __shared__ f16 pm[16 * YP];      // 18,432 B
  __shared__ float winv_s[16];
  const int tid = threadIdx.x;
  const int w = tid >> 6, l = tid & 63, lr = l & 15, lg = l >> 4;
  const int bh = blockIdx.y, x0 = blockIdx.x * 16;

  // Pre-zero padded tail (complete coverage with phase A's y=512 write; no race).
  for (int i = tid; i < 1024; i += 256) {
    int row = i >> 6, yo = i & 63;
    if (yo) pm[pmidx(row, 512 + yo)] = (f16)0.0f;
  }

  // ---- Phase A: |scores|/sqrt(E); wave w covers y in [w*144, w*144+ntile*16) ----
  const f16* qb = qf + ((size_t)bh * YP + x0 + lr) * 128 + lg * 8;
  f16x8 aq[4], aqs[4];
  #pragma unroll
  for (int c4 = 0; c4 < 4; c4++) {
    aq[c4] = *(const f16x8*)(qb + c4 * 32);
    u32x4 tt = *(const u32x4*)&aq[c4];
    u32x4 ss;
    #pragma unroll
    for (int d = 0; d < 4; d++)
      ss[d] = ((tt[d] >> 16) | (tt[d] << 16)) ^ 0x80000000u;  // (re,im)->(im,-re)
    aqs[c4] = *(const f16x8*)&ss;
  }

  const int ntile = (w == 3) ? 6 : 9;   // quarter 3 stops after the y=512 tile
  const f16* kb = kf + ((size_t)bh * YP + w * 144 + lr) * 128 + lg * 8;
  for (int t = 0; t < ntile; t++) {
    f16x8 bk[4];
    #pragma unroll
    for (int c4 = 0; c4 < 4; c4++)
      bk[c4] = *(const f16x8*)(kb + (size_t)t * 2048 + c4 * 32);
    f32x4 rr = {0.f,0.f,0.f,0.f}, ri = {0.f,0.f,0.f,0.f};
    #pragma unroll
    for (int c4 = 0; c4 < 4; c4++) {
      rr = __builtin_amdgcn_mfma_f32_16x16x32_f16(aq[c4],  bk[c4], rr, 0, 0, 0);
      ri = __builtin_amdgcn_mfma_f32_16x16x32_f16(aqs[c4], bk[c4], ri, 0, 0, 0);
    }
    int y = w * 144 + t * 16 + lr;
    if (y <= 512) {
      int rowb = lg * 4;
      #pragma unroll
      for (int i = 0; i < 4; i++)
        pm[pmidx(rowb + i, y)] = (f16)(0.125f * sqrtf(rr[i]*rr[i] + ri[i]*ri[i]));
    }
  }
  __syncthreads();

  // ---- Phase B: per-row softmax (wave w owns rows w*4..w*4+3) ----
  #pragma unroll 1
  for (int r = 0; r < 4; r++) {
    const int row = w * 4 + r;
    float mx = 0.0f;
    #pragma unroll
    for (int ps = 0; ps < 4; ps++) {
      __half2 hv = *(const __half2*)&pm[pmidx(row, 2 * (l + 64 * ps))];
      float2 f = __half22float2(hv);
      mx = fmaxf(mx, fmaxf(f.x, f.y));
    }
    if (l < 32) {
      __half2 hv = *(const __half2*)&pm[pmidx(row, 512 + 2 * l)];
      float2 f = __half22float2(hv);
      mx = fmaxf(mx, fmaxf(f.x, f.y));
    }
    #pragma unroll
    for (int o = 32; o > 0; o >>= 1) mx = fmaxf(mx, __shfl_xor(mx, o));

    float s = 0.0f;
    #pragma unroll
    for (int ps = 0; ps < 4; ps++) {
      int y = 2 * (l + 64 * ps);
      __half2 hv = *(const __half2*)&pm[pmidx(row, y)];
      float2 f = __half22float2(hv);
      float p0 = __expf(f.x - mx), p1 = __expf(f.y - mx);
      s += p0 + p1;
      *(__half2*)&pm[pmidx(row, y)] = __floats2half2_rn(p0, p1);
    }
    if (l < 32) {
      int y = 512 + 2 * l;
      __half2 hv = *(const __half2*)&pm[pmidx(row, y)];
      float2 f = __half22float2(hv);
      float p0 = (y <= 512) ? __expf(f.x - mx) : 0.0f;
      s += p0;
      *(__half2*)&pm[pmidx(row, y)] = __floats2half2_rn(p0, 0.0f);
    }
    #pragma unroll
    for (int o = 32; o > 0; o >>= 1) s += __shfl_xor(s, o);
    if (l == 0) winv_s[row] = 1.0f / s;
  }
  __syncthreads();

  // ---- Phase C: PV; wave w owns 32 output cols ----
  const int ch = w * 32;
  f32x4 acc[2];
  #pragma unroll
  for (int nt = 0; nt < 2; nt++) acc[nt] = (f32x4){0.f,0.f,0.f,0.f};
  const f16* vb = vfT + ((size_t)bh * 128 + ch + lr) * YP + lg * 8;
  for (int kc = 0; kc < 18; kc++) {
    f16x8 a = *(const f16x8*)&pm[pmidx(lr, kc * 32 + lg * 8)];
    #pragma unroll
    for (int nt = 0; nt < 2; nt++) {
      f16x8 b = *(const f16x8*)(vb + (size_t)(nt * 16) * YP + kc * 32);
      acc[nt] = __builtin_amdgcn_mfma_f32_16x16x32_f16(a, b, acc[nt], 0, 0, 0);
    }
  }
  #pragma unroll
  for (int i = 0; i < 4; i++) {
    int xl = lg * 4 + i;
    int x = x0 + xl;
    if (x < LF) {
      float wv = winv_s[xl];
      #pragma unroll
      for (int nt = 0; nt < 2; nt++)
        of[((size_t)bh * LF + x) * 128 + ch + nt * 16 + lr] = acc[nt][i] * wv;
    }
  }
}

// ---------------- K3: irfft via conjugate-symmetric packing --------------------
// Block = (equad: 4 e-values = 2 packed inverse FFTs, bh).
__global__ __launch_bounds__(512) void irfft_kernel(
    const float* __restrict__ of, float* __restrict__ out) {
  __shared__ float2 fb0[2048];
  __shared__ float2 fb1[2048];
  __shared__ float2 tw[768];
  const int t = threadIdx.x;
  const int equad = blockIdx.x;   // 0..15
  const int bh = blockIdx.y;      // 0..63
  const int b = bh >> 3, h = bh & 7;
  const int e0 = equad * 4;

  for (int i = t; i < 768; i += 512) {
    float sv, cv;
    __sincosf(6.2831853071795864769f * (float)i * (1.0f / 1024.0f), &sv, &cv);
    tw[i] = make_float2(cv, sv);
  }
  #pragma unroll
  for (int i = 0; i < 2; i++) {
    int kk = t + i * 512;
    if (kk <= 512) {
      const float* pr = of + ((size_t)bh * LF + kk) * 128 + e0 * 2;
      float4 r0 = *(const float4*)pr;
      float4 r1 = *(const float4*)(pr + 4);
      fb0[SW(kk)]        = make_float2(r0.x - r0.w, r0.y + r0.z);
      fb0[1024 + SW(kk)] = make_float2(r1.x - r1.w, r1.y + r1.z);
      if (kk >= 1 && kk <= 511) {
        fb0[SW(1024 - kk)]        = make_float2(r0.x + r0.w, r0.z - r0.y);
        fb0[1024 + SW(1024 - kk)] = make_float2(r1.x + r1.w, r1.z - r1.y);
      }
    }
  }
  __syncthreads();
  fft1024x2_r4(fb0, fb1, tw, t, +1.0f);
  #pragma unroll
  for (int i = 0; i < 2; i++) {
    int l = t + i * 512;
    float2 z0 = fb1[SW(l)], z1 = fb1[1024 + SW(l)];
    float4 o = make_float4(0.03125f * z0.x, 0.03125f * z0.y,
                           0.03125f * z1.x, 0.03125f * z1.y);
    *(float4*)(out + (((size_t)b * LSEQ + l) * NH + h) * EDIM + e0) = o;
  }
}

extern "C" void kernel_launch(void* const* d_in, const int* in_sizes, int n_in,
                              void* d_out, int out_size, void* d_ws, size_t ws_size,
                              hipStream_t stream) {
  const float* q = (const float*)d_in[0];
  const float* k = (const float*)d_in[1];
  const float* v = (const float*)d_in[2];
  float* out = (float*)d_out;
  char* ws = (char*)d_ws;

  // Workspace layout (bytes):
  //   qf16 : [0,          9437184)   64*576*128 fp16
  //   kf16 : [9437184,   18874368)
  //   vfT  : [18874368,  28311552)   64*128*576 fp16 (transposed, y-padded)
  //   of   : [28311552,  45121536)   64*513*128 fp32
  f16*   qf  = (f16*)(ws);
  f16*   kf  = (f16*)(ws + 9437184);
  f16*   vfT = (f16*)(ws + 18874368);
  float* of  = (float*)(ws + 28311552);

  rfft_pack_kernel<<<dim3(16, NBH, 3), 512, 0, stream>>>(q, k, v, qf, kf, vfT);
  fused_attn_kernel<<<dim3(33, NBH), 256, 0, stream>>>(qf, kf, vfT, of);
  irfft_kernel<<<dim3(16, NBH), 512, 0, stream>>>(of, out);
}